// Round 7
// baseline (141.550 us; speedup 1.0000x reference)
//
#include <hip/hip_runtime.h>
#include <hip/hip_bf16.h>

typedef __attribute__((ext_vector_type(8))) short short8;
typedef __attribute__((ext_vector_type(4))) float f32x4;

static __device__ __forceinline__ unsigned short f2bf(float f){
  union { float f; unsigned int u; } v; v.f = f;
  unsigned int r = v.u + 0x7fffu + ((v.u >> 16) & 1u);
  return (unsigned short)(r >> 16);
}
static __device__ __forceinline__ float bf2f(unsigned short u){
  union { unsigned int u; float f; } v; v.u = ((unsigned int)u) << 16; return v.f;
}

static __device__ __forceinline__ void load_lds16(const unsigned short* g, unsigned short* l){
  __builtin_amdgcn_global_load_lds(
      (const __attribute__((address_space(1))) unsigned int*)(g),
      (__attribute__((address_space(3))) unsigned int*)(l), 16, 0, 0);
}

// ---------------- kernel 1: x fp32 -> bf16 ----------------
__global__ void k_cvt_x(const float* __restrict__ x, unsigned short* __restrict__ xb){
  int i = (blockIdx.x * 256 + threadIdx.x) * 8;
  float4 a = *(const float4*)(x + i);
  float4 b = *(const float4*)(x + i + 4);
  unsigned short h[8];
  h[0]=f2bf(a.x); h[1]=f2bf(a.y); h[2]=f2bf(a.z); h[3]=f2bf(a.w);
  h[4]=f2bf(b.x); h[5]=f2bf(b.y); h[6]=f2bf(b.z); h[7]=f2bf(b.w);
  *(uint4*)(xb + i) = *(uint4*)h;
}

// ---------------- kernel 2: W -> Wt bf16 [p][d][e], bias concat ----------------
__global__ void k_prep_w(const float* __restrict__ Wq, const float* __restrict__ Wk,
                         const float* __restrict__ Wv,
                         const float* __restrict__ bq, const float* __restrict__ bk,
                         const float* __restrict__ bv,
                         unsigned short* __restrict__ Wt, float* __restrict__ bias){
  int gid = blockIdx.x * 256 + threadIdx.x;    // 0 .. 393215
  int p = gid >> 17;
  int rem = gid & 131071;
  int d = rem >> 10, e = rem & 1023;
  const float* W = (p==0) ? Wq : ((p==1) ? Wk : Wv);
  Wt[gid] = f2bf(W[e*128 + d]);                 // Wt[p][d][e] = W[e][d]
  if (gid < 384){
    int pp = gid >> 7, dd = gid & 127;
    bias[gid] = (pp==0) ? bq[dd] : ((pp==1) ? bk[dd] : bv[dd]);
  }
}

// ---------------- kernel 3: QKV GEMM, 64x128 tile, fused swizzled epilogue -----
// grid (128 mt, 3 p) = 384 blocks. Layouts:
//   Qsw/Ksw: [rowtile16][kc(4)][quad(4)][l16(16)][8]
//   Vsw:     [b][t64][nt(8)][kc2(2)][quad(4)][l16(16)][8]
__global__ __launch_bounds__(256) void k_gemm_qkv(
    const unsigned short* __restrict__ Xb, const unsigned short* __restrict__ Wt,
    const float* __restrict__ bias,
    unsigned short* __restrict__ Qsw, unsigned short* __restrict__ Ksw,
    unsigned short* __restrict__ Vsw){
  __shared__ __align__(16) unsigned short As[64*64];    // 8 KB
  __shared__ __align__(16) unsigned short Bs[128*64];   // 16 KB
  int tid = threadIdx.x;
  int m0 = blockIdx.x * 64;
  int p  = blockIdx.y;
  int w = tid >> 6, lane = tid & 63, quad = lane >> 4, l16 = lane & 15;
  int wm = (w & 1) * 32, wn = (w >> 1) * 64;
  f32x4 acc[2][4];
  #pragma unroll
  for (int i=0;i<2;i++)
    #pragma unroll
    for (int j=0;j<4;j++) acc[i][j] = (f32x4){0.f,0.f,0.f,0.f};

  const unsigned short* Wp = Wt + p * (128*1024);
  // wave w stages A rows [w*16, w*16+16), B rows [w*32, w*32+32)
  const unsigned short* Ag = Xb + (m0 + w*16 + (lane>>3))*1024 + (lane&7)*8;
  const unsigned short* Bg = Wp + (w*32 + (lane>>3))*1024 + (lane&7)*8;
  unsigned short* Al = As + w*16*64;   // wave-uniform base; HW adds lane*16B
  unsigned short* Bl = Bs + w*32*64;

  for (int k0 = 0; k0 < 1024; k0 += 64){
    load_lds16(Ag + k0,        Al);
    load_lds16(Ag + k0 + 8192, Al + 512);
    #pragma unroll
    for (int s=0; s<4; s++)
      load_lds16(Bg + k0 + s*8192, Bl + s*512);
    __syncthreads();
    #pragma unroll
    for (int kk=0; kk<64; kk+=32){
      short8 af[2], bf[4];
      #pragma unroll
      for (int i=0;i<2;i++) af[i] = *(const short8*)(As + (wm + i*16 + l16)*64 + kk + quad*8);
      #pragma unroll
      for (int j=0;j<4;j++) bf[j] = *(const short8*)(Bs + (wn + j*16 + l16)*64 + kk + quad*8);
      #pragma unroll
      for (int i=0;i<2;i++)
        #pragma unroll
        for (int j=0;j<4;j++)
          acc[i][j] = __builtin_amdgcn_mfma_f32_16x16x32_bf16(af[i], bf[j], acc[i][j], 0,0,0);
    }
    __syncthreads();
  }
  const float qscale = 0.08838834764831845f;  // 1/sqrt(128) folded into Q
  if (p < 2){
    unsigned short* dst = (p==0)? Qsw : Ksw;
    float scale = (p==0)? qscale : 1.0f;
    #pragma unroll
    for (int i=0;i<2;i++){
      #pragma unroll
      for (int j=0;j<4;j++){
        int col = wn + j*16 + l16;
        float bv_ = bias[p*128 + col];
        int kc = col >> 5, q2 = (col >> 3) & 3, jj = col & 7;
        #pragma unroll
        for (int r=0;r<4;r++){
          int row = m0 + wm + i*16 + quad*4 + r;   // C/D: row = quad*4+reg, col = l16
          int rt = row >> 4, m = row & 15;
          dst[rt*2048 + kc*512 + q2*128 + m*8 + jj] = f2bf((acc[i][j][r] + bv_)*scale);
        }
      }
    }
  } else {
    #pragma unroll
    for (int i=0;i<2;i++){
      int row0 = m0 + wm + i*16 + quad*4;
      int bb = row0 >> 11, s = row0 & 2047;
      int t64 = s >> 6, srem = s & 63;      // srem = wm+i*16+quad*4 (m0 mult of 64)
      int kc2 = srem >> 5, q2v = (srem >> 3) & 3, jjb = srem & 7;  // jjb = (quad&1)*4; r adds, no carry
      #pragma unroll
      for (int j=0;j<4;j++){
        int col = wn + j*16 + l16;
        float bv_ = bias[256 + col];
        int nt = (wn + j*16) >> 4;
        unsigned short pk[4];
        #pragma unroll
        for (int r=0;r<4;r++) pk[r] = f2bf(acc[i][j][r] + bv_);
        *(uint2*)(Vsw + (bb*32+t64)*8192 + nt*1024 + kc2*512 + q2v*128 + l16*8 + jjb) = *(uint2*)pk;
      }
    }
  }
}

// ---------------- kernel 4a: attention partial, flat jobs, 1-wave blocks -------
// Job = (b, 32 q-rows, chunk of <=4 kv-tiles). S^T = K@Q^T so softmax reductions
// are in-register (+2 shuffles). K/V fragments shared across the 2 q-subtiles.
// Partial slot (8448 B): O bf16 [2][8][lane][4] C-layout-packed, then m,l f32[2][16].
__global__ __launch_bounds__(64) void k_attn(
    const unsigned short* __restrict__ Qsw, const unsigned short* __restrict__ Ksw,
    const unsigned short* __restrict__ Vsw, unsigned short* __restrict__ Apart){
  __shared__ __align__(16) unsigned short Pw[2*16*80];
  int x = blockIdx.x;
  int b = x & 3;
  int t = x >> 2;
  int c = t & 7;
  int qb = 63 - (t >> 3);              // heavy q-blocks first
  int T32 = (qb >> 1) + 1;             // kv tiles covering keys <= qb*32+31
  int nch = (T32 + 3) >> 2;
  if (c >= nch) return;
  int lane = threadIdx.x;
  int quad = lane >> 4, l16 = lane & 15;
  int q0 = qb * 32;

  short8 aq[2][4];
  #pragma unroll
  for (int s=0;s<2;s++)
    #pragma unroll
    for (int kc=0;kc<4;kc++)
      aq[s][kc] = *(const short8*)(Qsw + (b*128 + qb*2 + s)*2048 + kc*512 + lane*8);

  f32x4 o[2][8];
  #pragma unroll
  for (int s=0;s<2;s++)
    #pragma unroll
    for (int i=0;i<8;i++) o[s][i] = (f32x4){0.f,0.f,0.f,0.f};
  float mcol[2] = {-1e30f,-1e30f};
  float lcol[2] = {0.f,0.f};
  short8 ap[2][2];

  const unsigned short* Kb = Ksw + b*128*2048;
  const unsigned short* Vb = Vsw + b*32*8192;

  int tEnd = (T32 < c*4+4) ? T32 : (c*4+4);
  for (int tt = c*4; tt < tEnd; tt++){
    int t0 = tt * 64;
    // S^T = K @ Q^T : A = K frags (m=key), B = Q frags (n=q). C: row=key, col=q.
    f32x4 sc[2][4];
    #pragma unroll
    for (int s=0;s<2;s++)
      #pragma unroll
      for (int nt=0;nt<4;nt++) sc[s][nt] = (f32x4){0.f,0.f,0.f,0.f};
    #pragma unroll
    for (int nt=0;nt<4;nt++){
      const unsigned short* Kt = Kb + ((t0>>4)+nt)*2048 + lane*8;
      #pragma unroll
      for (int kc=0;kc<4;kc++){
        short8 kf = *(const short8*)(Kt + kc*512);
        sc[0][nt] = __builtin_amdgcn_mfma_f32_16x16x32_bf16(kf, aq[0][kc], sc[0][nt], 0,0,0);
        sc[1][nt] = __builtin_amdgcn_mfma_f32_16x16x32_bf16(kf, aq[1][kc], sc[1][nt], 0,0,0);
      }
    }
    #pragma unroll
    for (int s=0;s<2;s++){
      int qs = q0 + s*16;               // q rows qs..qs+15; our q col = qs + l16
      if (t0 + 63 > qs){                // mask needed iff tile's max key > subtile's MIN q
        #pragma unroll
        for (int nt=0;nt<4;nt++){
          int kb_ = t0 + nt*16 + quad*4;
          #pragma unroll
          for (int r=0;r<4;r++)
            if (kb_ + r > qs + l16) sc[s][nt][r] = -1e30f;
        }
      }
      // in-register max over 16 keys, then 2 shuffles across quads
      float mt_ = -1e30f;
      #pragma unroll
      for (int nt=0;nt<4;nt++)
        #pragma unroll
        for (int r=0;r<4;r++) mt_ = fmaxf(mt_, sc[s][nt][r]);
      mt_ = fmaxf(mt_, __shfl_xor(mt_, 16));
      mt_ = fmaxf(mt_, __shfl_xor(mt_, 32));
      float mn = fmaxf(mcol[s], mt_);
      float al = __expf(mcol[s] - mn);
      mcol[s] = mn;
      float ls = 0.f;
      #pragma unroll
      for (int nt=0;nt<4;nt++)
        #pragma unroll
        for (int r=0;r<4;r++){
          float pv = __expf(sc[s][nt][r] - mn);
          sc[s][nt][r] = pv;
          ls += pv;
        }
      ls += __shfl_xor(ls, 16);
      ls += __shfl_xor(ls, 32);
      lcol[s] = lcol[s]*al + ls;
      // rescale O: alpha indexed by q-row = quad*4+r -> fetch from lane l16=quad*4+r
      #pragma unroll
      for (int r=0;r<4;r++){
        float ar = __shfl(al, quad*4 + r);
        #pragma unroll
        for (int nt=0;nt<8;nt++) o[s][nt][r] *= ar;
      }
      // P^T (C-layout) -> P A-layout: packed b64 writes then b128 reads
      unsigned short* Pws = Pw + s*1280;
      #pragma unroll
      for (int nt=0;nt<4;nt++){
        unsigned short pk[4];
        #pragma unroll
        for (int r=0;r<4;r++) pk[r] = f2bf(sc[s][nt][r]);
        *(uint2*)(Pws + l16*80 + nt*16 + quad*4) = *(uint2*)pk;
      }
      ap[s][0] = *(const short8*)(Pws + l16*80 + quad*8);
      ap[s][1] = *(const short8*)(Pws + l16*80 + 32 + quad*8);
    }
    // O += P @ V ; V fragments shared by both subtiles
    const unsigned short* Vt0 = Vb + (t0>>6)*8192 + lane*8;
    #pragma unroll
    for (int nt=0; nt<8; nt++)
      #pragma unroll
      for (int kc2=0;kc2<2;kc2++){
        short8 vf = *(const short8*)(Vt0 + nt*1024 + kc2*512);
        o[0][nt] = __builtin_amdgcn_mfma_f32_16x16x32_bf16(ap[0][kc2], vf, o[0][nt], 0,0,0);
        o[1][nt] = __builtin_amdgcn_mfma_f32_16x16x32_bf16(ap[1][kc2], vf, o[1][nt], 0,0,0);
      }
  }

  // store partial: O as packed bf16 (coalesced uint2), m/l f32
  unsigned short* slot = Apart + (size_t)(((b*64 + qb)*8 + c)) * 4224;
  #pragma unroll
  for (int s=0;s<2;s++)
    #pragma unroll
    for (int nt=0;nt<8;nt++){
      unsigned short pk[4];
      #pragma unroll
      for (int r=0;r<4;r++) pk[r] = f2bf(o[s][nt][r]);
      *(uint2*)(slot + (s*8+nt)*256 + lane*4) = *(uint2*)pk;
    }
  float* fslot = (float*)(slot + 4096);
  if (quad == 0){
    #pragma unroll
    for (int s=0;s<2;s++){
      fslot[s*16 + l16]      = mcol[s];
      fslot[32 + s*16 + l16] = lcol[s];
    }
  }
}

// ---------------- kernel 4b: combine attention chunks ----------------
__global__ __launch_bounds__(256) void k_acomb(const unsigned short* __restrict__ Apart,
                                               float* __restrict__ out){
  int b = blockIdx.x & 3, qb = blockIdx.x >> 2;
  int T32 = (qb >> 1) + 1;
  int nch = (T32 + 3) >> 2;
  const unsigned short* slot0 = Apart + (size_t)((b*64 + qb)*8) * 4224;
  int tid = threadIdx.x;
  int row = tid >> 3;              // 0..31
  int c0 = (tid & 7) * 16;         // 16 cols per thread
  int s = row >> 4, qrow = row & 15;
  int quad = qrow >> 2, r = qrow & 3;
  int nt = c0 >> 4;
  float m = -1e30f;
  for (int c=0;c<nch;c++){
    const float* fs = (const float*)(slot0 + c*4224 + 4096);
    m = fmaxf(m, fs[s*16 + qrow]);
  }
  float acc[16];
  #pragma unroll
  for (int k=0;k<16;k++) acc[k] = 0.f;
  float lsum = 0.f;
  for (int c=0;c<nch;c++){
    const float* fs = (const float*)(slot0 + c*4224 + 4096);
    float e = __expf(fs[s*16 + qrow] - m);
    lsum += fs[32 + s*16 + qrow] * e;
    const unsigned short* ob = slot0 + c*4224 + (s*8+nt)*256 + quad*64 + r;
    #pragma unroll
    for (int k=0;k<16;k++)
      acc[k] += bf2f(ob[k*4]) * e;
  }
  float inv = 1.0f / lsum;
  float* op = out + (size_t)(b*2048 + qb*32 + row)*128 + c0;
  #pragma unroll
  for (int g=0;g<4;g++){
    float4 rv = {acc[g*4]*inv, acc[g*4+1]*inv, acc[g*4+2]*inv, acc[g*4+3]*inv};
    *(float4*)(op + g*4) = rv;
  }
}

extern "C" void kernel_launch(void* const* d_in, const int* in_sizes, int n_in,
                              void* d_out, int out_size, void* d_ws, size_t ws_size,
                              hipStream_t stream) {
  const float* x  = (const float*)d_in[0];
  const float* Wq = (const float*)d_in[1];
  const float* bq = (const float*)d_in[2];
  const float* Wk = (const float*)d_in[3];
  const float* bk = (const float*)d_in[4];
  const float* Wv = (const float*)d_in[5];
  const float* bv = (const float*)d_in[6];
  char* ws = (char*)d_ws;
  unsigned short* Xb   = (unsigned short*)(ws);             // 16,777,216 B
  unsigned short* Wt   = (unsigned short*)(ws + 16777216);  //    786,432 B
  float*          bias = (float*)(ws + 17563648);           //      1,536 B
  unsigned short* Qsw  = (unsigned short*)(ws + 17565184);  //  2,097,152 B
  unsigned short* Ksw  = (unsigned short*)(ws + 19662336);  //  2,097,152 B
  unsigned short* Vsw  = (unsigned short*)(ws + 21759488);  //  2,097,152 B
  unsigned short* Apart= (unsigned short*)(ws + 23856640);  // 17,301,504 B (2048 x 8448)
  float* out = (float*)d_out;

  hipLaunchKernelGGL(k_cvt_x,   dim3(4096),    dim3(256), 0, stream, x, Xb);
  hipLaunchKernelGGL(k_prep_w,  dim3(1536),    dim3(256), 0, stream, Wq, Wk, Wv, bq, bk, bv, Wt, bias);
  hipLaunchKernelGGL(k_gemm_qkv,dim3(128,3),   dim3(256), 0, stream, Xb, Wt, bias, Qsw, Ksw, Vsw);
  hipLaunchKernelGGL(k_attn,    dim3(2048),    dim3(64),  0, stream, Qsw, Ksw, Vsw, Apart);
  hipLaunchKernelGGL(k_acomb,   dim3(256),     dim3(256), 0, stream, Apart, out);
}